// Round 11
// baseline (1198.175 us; speedup 1.0000x reference)
//
#include <hip/hip_runtime.h>
#include <stdint.h>

typedef float    f32x4  __attribute__((ext_vector_type(4)));
typedef float    f32x16 __attribute__((ext_vector_type(16)));
typedef __bf16   bf16x8 __attribute__((ext_vector_type(8)));
typedef unsigned int u32x4 __attribute__((ext_vector_type(4)));
typedef unsigned short ushort_t;

#define NB     65536
#define NSTEPS 40

// ws layout: [kt 0..39][g 0..2][n 0..255][128 B row]
// row = 8 chunks of 16 B, UNswizzled: chunk c (0..3 = hi k c*8..c*8+8, 4..7 = lo)
#define WS_B_BYTES (40ull * 3ull * 256ull * 128ull)   // 3,932,160

union Frag8 { ushort_t u[8]; u32x4 q; bf16x8 v; };

static __device__ __forceinline__ ushort_t bf16_rne(float x) {
  uint32_t u = __float_as_uint(x);
  u += 0x7FFFu + ((u >> 16) & 1u);
  return (ushort_t)(u >> 16);
}
static __device__ __forceinline__ float bf16_f(ushort_t h) {
  return __uint_as_float(((uint32_t)h) << 16);
}

// ============================ prep: pack weights ============================
__global__ __launch_bounds__(256)
void prep_weights(const float* __restrict__ Wi, const float* __restrict__ Wo,
                  const float* __restrict__ Wu,
                  const float* __restrict__ Ui, const float* __restrict__ Uo,
                  const float* __restrict__ Uu,
                  char* __restrict__ wsB)
{
  const int idx = blockIdx.x * 256 + threadIdx.x;   // 122880 total
  const int qq = idx & 3;
  const int n  = (idx >> 2) & 255;
  const int t  = idx >> 10;        // kt*3 + g
  const int g  = t % 3;
  const int kt = t / 3;
  const float* Wg = (g == 0) ? Wi : (g == 1) ? Wo : Wu;
  const float* Ug = (g == 0) ? Ui : (g == 1) ? Uo : Uu;
  const int k0 = kt * 32 + qq * 8;
  const float* src;
  if (k0 < 256) {
    src = Wg + (size_t)n * 256 + k0;
  } else {
    const int kc = (k0 - 256) >> 8;
    const int m  = (k0 - 256) & 255;
    src = Ug + (size_t)kc * 65536 + (size_t)n * 256 + m;
  }
  f32x4 a = *(const f32x4*)src;
  f32x4 b = *(const f32x4*)(src + 4);
  Frag8 hi, lo;
  #pragma unroll
  for (int j = 0; j < 4; ++j) {
    ushort_t h0 = bf16_rne(a[j]);
    hi.u[j] = h0; lo.u[j] = bf16_rne(a[j] - bf16_f(h0));
    ushort_t h1 = bf16_rne(b[j]);
    hi.u[4 + j] = h1; lo.u[4 + j] = bf16_rne(b[j] - bf16_f(h1));
  }
  char* base = wsB + ((size_t)t * 256 + n) * 128;
  *(u32x4*)(base + (qq << 4))       = hi.q;
  *(u32x4*)(base + ((qq | 4) << 4)) = lo.q;
}

// ====== v11: ZERO LDS, ZERO barriers — per-wave independent 32x32x3 tiles ======
// B frags read directly global->reg from the pre-packed ws image (L1/L2-resident);
// A loaded global->reg and hi/lo split in-register. Waves free-run (m114 overlap).
__global__ __launch_bounds__(256, 4)
void treelstm_fused_v11(const float* __restrict__ inputs,
                        const float* __restrict__ children,
                        const char*  __restrict__ wsB,
                        const float* __restrict__ bi, const float* __restrict__ bo,
                        const float* __restrict__ bu,
                        float* __restrict__ out)
{
  const int tid = threadIdx.x;
  const int bid = blockIdx.x;
  // XCD-bijective swizzle over 4096 blocks: XCD x gets wg [x*512, (x+1)*512)
  const int wg      = (bid & 7) * 512 + (bid >> 3);
  const int colhalf = wg >> 11;        // 0..1  (XCDs 0-3 -> half 0, 4-7 -> half 1)
  const int rowblk  = wg & 2047;       // 0..2047
  const int lane = tid & 63;
  const int wid  = tid >> 6;           // 0..3
  const int cg   = colhalf * 4 + wid;  // 0..7 col-group (32 cols per gate)
  const int l31  = lane & 31;
  const int lh   = lane >> 5;          // k-half selector

  const int row  = rowblk * 32 + l31;  // A row owned by this lane
  const int ncol = cg * 32 + l31;      // B col / output col

  f32x16 acc[3];
  #pragma unroll
  for (int g = 0; g < 3; ++g)
    #pragma unroll
    for (int r = 0; r < 16; ++r)
      acc[g][r] = 0.f;

  // per-lane B base: + s*98304 + g*32768 + imm{0,32,64,96}
  const char* wsL = wsB + (size_t)ncol * 128 + lh * 16;

  // per-lane A base for step s (16 fp32: kk0 at +0, kk1 at +16)
  auto aPtr = [&](int s) -> const float* {
    if (s < 8) return inputs + (size_t)row * 256 + s * 32 + lh * 8;
    const int ss = s - 8;
    return children + ((size_t)(ss >> 3) * NB + (size_t)row) * 512 + (ss & 7) * 32 + lh * 8;
  };

  // A(next) fp32 pipeline registers
  f32x4 n0, n1, n2, n3;
  { const float* p = aPtr(0);
    n0 = *(const f32x4*)p;        n1 = *(const f32x4*)(p + 4);
    n2 = *(const f32x4*)(p + 16); n3 = *(const f32x4*)(p + 20); }

  #pragma unroll 1
  for (int s = 0; s < NSTEPS; ++s) {
    // convert A(s) fp32 -> hi/lo frags (v_cvt_pk_bf16_f32 path)
    Frag8 a00, a01, a10, a11;   // kk0-hi, kk1-hi, kk0-lo, kk1-lo
    #pragma unroll
    for (int j = 0; j < 4; ++j) {
      __bf16 h;
      h = (__bf16)n0[j]; a00.v[j]     = h; a10.v[j]     = (__bf16)(n0[j] - (float)h);
      h = (__bf16)n1[j]; a00.v[4 + j] = h; a10.v[4 + j] = (__bf16)(n1[j] - (float)h);
      h = (__bf16)n2[j]; a01.v[j]     = h; a11.v[j]     = (__bf16)(n2[j] - (float)h);
      h = (__bf16)n3[j]; a01.v[4 + j] = h; a11.v[4 + j] = (__bf16)(n3[j] - (float)h);
    }
    // issue A(s+1) loads (latency hides under this step's B-loads + MFMA)
    { const int sn = (s + 1 < NSTEPS) ? s + 1 : NSTEPS - 1;
      const float* p = aPtr(sn);
      n0 = *(const f32x4*)p;        n1 = *(const f32x4*)(p + 4);
      n2 = *(const f32x4*)(p + 16); n3 = *(const f32x4*)(p + 20); }

    const char* wsS = wsL + (size_t)s * 98304;
    #pragma unroll
    for (int g = 0; g < 3; ++g) {
      Frag8 b00, b01, b10, b11;
      const char* pb = wsS + g * 32768;
      b00.q = *(const u32x4*)(pb);        // kk0 hi
      b01.q = *(const u32x4*)(pb + 32);   // kk1 hi
      b10.q = *(const u32x4*)(pb + 64);   // kk0 lo
      b11.q = *(const u32x4*)(pb + 96);   // kk1 lo
      acc[g] = __builtin_amdgcn_mfma_f32_32x32x16_bf16(a00.v, b00.v, acc[g], 0, 0, 0);
      acc[g] = __builtin_amdgcn_mfma_f32_32x32x16_bf16(a10.v, b00.v, acc[g], 0, 0, 0);
      acc[g] = __builtin_amdgcn_mfma_f32_32x32x16_bf16(a00.v, b10.v, acc[g], 0, 0, 0);
      acc[g] = __builtin_amdgcn_mfma_f32_32x32x16_bf16(a01.v, b01.v, acc[g], 0, 0, 0);
      acc[g] = __builtin_amdgcn_mfma_f32_32x32x16_bf16(a11.v, b01.v, acc[g], 0, 0, 0);
      acc[g] = __builtin_amdgcn_mfma_f32_32x32x16_bf16(a01.v, b11.v, acc[g], 0, 0, 0);
    }
  }

  // ---- epilogue: C/D map col=lane&31, row=(r&3)+8*(r>>2)+4*lh (m74/m101-verified) ----
  {
    const float bin = bi[ncol], bon = bo[ncol], bun = bu[ncol];
    #pragma unroll
    for (int r = 0; r < 16; ++r) {
      const int orow = rowblk * 32 + (r & 3) + 8 * (r >> 2) + 4 * lh;
      const float iv = acc[0][r] + bin;
      const float ov = acc[1][r] + bon;
      const float uv = acc[2][r] + bun;
      const float tu = 1.f - 2.f / (1.f + __expf(2.f * uv));
      const float si = 1.f / (1.f + __expf(-iv));
      const float cv = si * tu;
      const float so = 1.f / (1.f + __expf(-ov));
      const float tc = 1.f - 2.f / (1.f + __expf(2.f * cv));
      const float hv = so * tc;
      const size_t base = (size_t)orow * 512 + (size_t)ncol;
      out[base]       = hv;
      out[base + 256] = cv;
    }
  }
}

// ================= v1 fallback (ws too small) =================
#define A_HI 0
#define A_LO 8192
#define B_HI 16384
#define B_LO 40960
typedef unsigned int u32x4_t __attribute__((ext_vector_type(4)));

__global__ __launch_bounds__(512, 2)
void treelstm_fused_v1(const float* __restrict__ inputs,
                       const float* __restrict__ children,
                       const float* __restrict__ Wi, const float* __restrict__ bi,
                       const float* __restrict__ Wo, const float* __restrict__ bo,
                       const float* __restrict__ Wu, const float* __restrict__ bu,
                       const float* __restrict__ Ui, const float* __restrict__ Uo,
                       const float* __restrict__ Uu,
                       float* __restrict__ out)
{
  __shared__ u32x4 lds_u4[4096];
  char* lds = (char*)lds_u4;
  const int tid = threadIdx.x;
  const int bid = blockIdx.x;
  const int wg     = (bid & 7) * 128 + (bid >> 3);
  const int strip  = wg >> 9;
  const int rowblk = wg & 511;
  const int b0 = rowblk * 128;
  const int n0 = strip * 128;
  const int rowA = tid >> 2;
  const int koff = (tid & 3) * 8;
  const float* Wg[3] = {Wi, Wo, Wu};
  const float* Ug[3] = {Ui, Uo, Uu};
  const int lane = tid & 63;
  const int wid  = tid >> 6;
  const int wr   = wid >> 2;
  const int wc   = wid & 3;
  const int lc   = lane & 15;
  const int qq   = lane >> 4;

  f32x4 acc[4][2][3];
  #pragma unroll
  for (int a = 0; a < 4; ++a)
    #pragma unroll
    for (int b = 0; b < 2; ++b)
      #pragma unroll
      for (int g = 0; g < 3; ++g)
        acc[a][b][g] = (f32x4){0.f, 0.f, 0.f, 0.f};

  float va[8];
  float vb[3][8];

  auto loadStep = [&](int s) {
    const int k0 = s * 32;
    const float* pa;
    if (s < 8) pa = inputs + (size_t)(b0 + rowA) * 256 + (k0 + koff);
    else {
      const int kc = (s - 8) >> 3;
      const int m0 = ((s - 8) & 7) * 32;
      pa = children + ((size_t)kc * NB + (size_t)(b0 + rowA)) * 512 + (m0 + koff);
    }
    f32x4 t0 = *(const f32x4*)pa;
    f32x4 t1 = *(const f32x4*)(pa + 4);
    #pragma unroll
    for (int j = 0; j < 4; ++j) { va[j] = t0[j]; va[4 + j] = t1[j]; }
    #pragma unroll
    for (int g = 0; g < 3; ++g) {
      const float* pb;
      if (s < 8) pb = Wg[g] + (size_t)(n0 + rowA) * 256 + (k0 + koff);
      else {
        const int kc = (s - 8) >> 3;
        const int m0 = ((s - 8) & 7) * 32;
        pb = Ug[g] + (size_t)kc * 65536 + (size_t)(n0 + rowA) * 256 + (m0 + koff);
      }
      f32x4 u0 = *(const f32x4*)pb;
      f32x4 u1 = *(const f32x4*)(pb + 4);
      #pragma unroll
      for (int j = 0; j < 4; ++j) { vb[g][j] = u0[j]; vb[g][4 + j] = u1[j]; }
    }
  };

  auto storeStep = [&]() {
    Frag8 h, l;
    #pragma unroll
    for (int j = 0; j < 8; ++j) {
      ushort_t hb = bf16_rne(va[j]);
      h.u[j] = hb;
      l.u[j] = bf16_rne(va[j] - bf16_f(hb));
    }
    *(u32x4*)(lds + A_HI + rowA * 64 + koff * 2) = h.q;
    *(u32x4*)(lds + A_LO + rowA * 64 + koff * 2) = l.q;
    #pragma unroll
    for (int g = 0; g < 3; ++g) {
      Frag8 hg, lg;
      #pragma unroll
      for (int j = 0; j < 8; ++j) {
        ushort_t hb = bf16_rne(vb[g][j]);
        hg.u[j] = hb;
        lg.u[j] = bf16_rne(vb[g][j] - bf16_f(hb));
      }
      *(u32x4*)(lds + B_HI + (g * 128 + rowA) * 64 + koff * 2) = hg.q;
      *(u32x4*)(lds + B_LO + (g * 128 + rowA) * 64 + koff * 2) = lg.q;
    }
  };

  auto computeStep = [&]() {
    Frag8 ah[4], al[4];
    #pragma unroll
    for (int rf = 0; rf < 4; ++rf) {
      const int r2 = wr * 64 + rf * 16 + lc;
      ah[rf].q = *(const u32x4*)(lds + A_HI + r2 * 64 + qq * 16);
      al[rf].q = *(const u32x4*)(lds + A_LO + r2 * 64 + qq * 16);
    }
    #pragma unroll
    for (int g = 0; g < 3; ++g) {
      #pragma unroll
      for (int cf = 0; cf < 2; ++cf) {
        const int col = wc * 32 + cf * 16 + lc;
        Frag8 bh, bl;
        bh.q = *(const u32x4*)(lds + B_HI + (g * 128 + col) * 64 + qq * 16);
        bl.q = *(const u32x4*)(lds + B_LO + (g * 128 + col) * 64 + qq * 16);
        #pragma unroll
        for (int rf = 0; rf < 4; ++rf) {
          acc[rf][cf][g] = __builtin_amdgcn_mfma_f32_16x16x32_bf16(ah[rf].v, bh.v, acc[rf][cf][g], 0, 0, 0);
          acc[rf][cf][g] = __builtin_amdgcn_mfma_f32_16x16x32_bf16(al[rf].v, bh.v, acc[rf][cf][g], 0, 0, 0);
          acc[rf][cf][g] = __builtin_amdgcn_mfma_f32_16x16x32_bf16(ah[rf].v, bl.v, acc[rf][cf][g], 0, 0, 0);
        }
      }
    }
  };

  loadStep(0);
  #pragma unroll 1
  for (int s = 0; s < NSTEPS; ++s) {
    if (s) __syncthreads();
    storeStep();
    __syncthreads();
    if (s + 1 < NSTEPS) loadStep(s + 1);
    computeStep();
  }

  #pragma unroll
  for (int cf = 0; cf < 2; ++cf) {
    const int n = n0 + wc * 32 + cf * 16 + lc;
    const float bin = bi[n], bon = bo[n], bun = bu[n];
    #pragma unroll
    for (int rf = 0; rf < 4; ++rf) {
      const int brow = b0 + wr * 64 + rf * 16 + qq * 4;
      #pragma unroll
      for (int r = 0; r < 4; ++r) {
        const float iv = acc[rf][cf][0][r] + bin;
        const float ov = acc[rf][cf][1][r] + bon;
        const float uv = acc[rf][cf][2][r] + bun;
        const float tu = 1.f - 2.f / (1.f + __expf(2.f * uv));
        const float si = 1.f / (1.f + __expf(-iv));
        const float cv = si * tu;
        const float so = 1.f / (1.f + __expf(-ov));
        const float tc = 1.f - 2.f / (1.f + __expf(2.f * cv));
        const float hv = so * tc;
        const size_t base = (size_t)(brow + r) * 512 + (size_t)n;
        out[base]       = hv;
        out[base + 256] = cv;
      }
    }
  }
}

extern "C" void kernel_launch(void* const* d_in, const int* in_sizes, int n_in,
                              void* d_out, int out_size, void* d_ws, size_t ws_size,
                              hipStream_t stream) {
  const float* inputs   = (const float*)d_in[0];
  const float* children = (const float*)d_in[1];
  const float* Wi = (const float*)d_in[3];
  const float* bi = (const float*)d_in[4];
  const float* Wo = (const float*)d_in[5];
  const float* bo = (const float*)d_in[6];
  const float* Wu = (const float*)d_in[7];
  const float* bu = (const float*)d_in[8];
  const float* Ui = (const float*)d_in[11];
  const float* Uo = (const float*)d_in[12];
  const float* Uu = (const float*)d_in[13];
  float* out = (float*)d_out;

  if (ws_size >= WS_B_BYTES) {
    char* wsB = (char*)d_ws;
    hipLaunchKernelGGL(prep_weights, dim3(480), dim3(256), 0, stream,
                       Wi, Wo, Wu, Ui, Uo, Uu, wsB);
    hipLaunchKernelGGL(treelstm_fused_v11, dim3(4096), dim3(256), 0, stream,
                       inputs, children, wsB, bi, bo, bu, out);
  } else {
    hipLaunchKernelGGL(treelstm_fused_v1, dim3(1024), dim3(512), 0, stream,
                       inputs, children, Wi, bi, Wo, bo, Wu, bu, Ui, Uo, Uu, out);
  }
}

// Round 12
// 377.038 us; speedup vs baseline: 3.1779x; 3.1779x over previous
//
#include <hip/hip_runtime.h>
#include <stdint.h>

typedef float    f32x4  __attribute__((ext_vector_type(4)));
typedef __bf16   bf16x8 __attribute__((ext_vector_type(8)));
typedef unsigned int u32x4 __attribute__((ext_vector_type(4)));
typedef unsigned short ushort_t;

#define NB     65536   // batch
#define BM     128     // rows per block
#define BK     32
#define NSTEPS 40      // 1280 / 32

// ---- v4 dynamic LDS layout (bytes): A dbuf 2x16K, B dbuf 2x48K = 128 KiB ----
#define LDS_A0 0
#define LDS_A1 16384
#define LDS_B0 32768
#define LDS_B1 81920
#define LDS_TOTAL 131072

// ws layout: [kt 0..39][g 0..2][n 0..255][128 B row], row = swizzled hi/lo image
#define WS_B_BYTES (40ull * 3ull * 256ull * 128ull)   // 3,932,160

union Frag8 { ushort_t u[8]; u32x4 q; bf16x8 v; };

static __device__ __forceinline__ ushort_t bf16_rne(float x) {
  uint32_t u = __float_as_uint(x);
  u += 0x7FFFu + ((u >> 16) & 1u);
  return (ushort_t)(u >> 16);
}
static __device__ __forceinline__ float bf16_f(ushort_t h) {
  return __uint_as_float(((uint32_t)h) << 16);
}

typedef const __attribute__((address_space(1))) void gas_void;
typedef __attribute__((address_space(3))) void las_void;

static __device__ __forceinline__ void glds16(const void* g, void* l) {
  __builtin_amdgcn_global_load_lds((gas_void*)g, (las_void*)l, 16, 0, 0);
}

// ---- compile-time-G helpers (rule #20: keep acc indices static) ----
template<int G>
static __device__ __forceinline__ void read_pair(const char* lds, int bufoff,
    int wc, int lc, int qq, Frag8 (&bh)[2], Frag8 (&bl)[2]) {
  #pragma unroll
  for (int cf = 0; cf < 2; ++cf) {
    const int col = wc * 32 + cf * 16 + lc;
    const char* p = lds + bufoff + G * 16384 + col * 128;
    const int sw = col & 7;
    bh[cf].q = *(const u32x4*)(p + ((qq ^ sw) << 4));
    bl[cf].q = *(const u32x4*)(p + (((qq | 4) ^ sw) << 4));
  }
}

template<int G>
static __device__ __forceinline__ void mfma_pair(f32x4 (&acc)[4][2][3],
    const Frag8 (&ah)[4], const Frag8 (&al)[4],
    const Frag8 (&bh)[2], const Frag8 (&bl)[2]) {
  #pragma unroll
  for (int cf = 0; cf < 2; ++cf) {
    #pragma unroll
    for (int rf = 0; rf < 4; ++rf) {
      acc[rf][cf][G] = __builtin_amdgcn_mfma_f32_16x16x32_bf16(ah[rf].v, bh[cf].v, acc[rf][cf][G], 0, 0, 0);
      acc[rf][cf][G] = __builtin_amdgcn_mfma_f32_16x16x32_bf16(al[rf].v, bh[cf].v, acc[rf][cf][G], 0, 0, 0);
      acc[rf][cf][G] = __builtin_amdgcn_mfma_f32_16x16x32_bf16(ah[rf].v, bl[cf].v, acc[rf][cf][G], 0, 0, 0);
    }
  }
}

// m201 phase discipline: barrier FIRST, then own-wave lgkm wait, then fence (rule #18)
#define PHASE_SYNC() do { \
    asm volatile("s_barrier" ::: "memory"); \
    asm volatile("s_waitcnt lgkmcnt(0)" ::: "memory"); \
    __builtin_amdgcn_sched_barrier(0); \
  } while (0)

// ============================ prep: pack weights ============================
__global__ __launch_bounds__(256)
void prep_weights(const float* __restrict__ Wi, const float* __restrict__ Wo,
                  const float* __restrict__ Wu,
                  const float* __restrict__ Ui, const float* __restrict__ Uo,
                  const float* __restrict__ Uu,
                  char* __restrict__ wsB)
{
  const int idx = blockIdx.x * 256 + threadIdx.x;   // 40*3*256*4 = 122880
  const int qq = idx & 3;
  const int n  = (idx >> 2) & 255;
  const int t  = idx >> 10;        // kt*3 + g, 0..119 (uniform per block)
  const int g  = t % 3;
  const int kt = t / 3;
  const float* Wg = (g == 0) ? Wi : (g == 1) ? Wo : Wu;
  const float* Ug = (g == 0) ? Ui : (g == 1) ? Uo : Uu;
  const int k0 = kt * 32 + qq * 8;
  const float* src;
  if (k0 < 256) {
    src = Wg + (size_t)n * 256 + k0;
  } else {
    const int kc = (k0 - 256) >> 8;
    const int m  = (k0 - 256) & 255;
    src = Ug + (size_t)kc * 65536 + (size_t)n * 256 + m;
  }
  f32x4 a = *(const f32x4*)src;
  f32x4 b = *(const f32x4*)(src + 4);
  Frag8 hi, lo;
  #pragma unroll
  for (int j = 0; j < 4; ++j) {
    ushort_t h0 = bf16_rne(a[j]);
    hi.u[j] = h0; lo.u[j] = bf16_rne(a[j] - bf16_f(h0));
    ushort_t h1 = bf16_rne(b[j]);
    hi.u[4 + j] = h1; lo.u[4 + j] = bf16_rne(b[j] - bf16_f(h1));
  }
  char* base = wsB + ((size_t)t * 256 + n) * 128;
  const int sw = n & 7;
  *(u32x4*)(base + ((qq ^ sw) << 4))       = hi.q;
  *(u32x4*)(base + (((qq | 4) ^ sw) << 4)) = lo.q;
}

// ============================ v4 main kernel ============================
__global__ __launch_bounds__(512, 2)
void treelstm_fused_v4(const float* __restrict__ inputs,
                       const float* __restrict__ children,
                       const char*  __restrict__ wsB,
                       const float* __restrict__ bi, const float* __restrict__ bo,
                       const float* __restrict__ bu,
                       float* __restrict__ out)
{
  extern __shared__ __align__(16) char lds[];

  const int tid = threadIdx.x;
  const int bid = blockIdx.x;
  // XCD-aware bijective swizzle (1024 blocks = 8 * 128)
  const int wg     = (bid & 7) * 128 + (bid >> 3);
  const int strip  = wg >> 9;
  const int rowblk = wg & 511;
  const int b0 = rowblk * BM;
  const int n0 = strip * 128;

  const int rowA = tid >> 2;       // 0..127
  const int ca   = tid & 3;        // A k-chunk 0..3
  const int lane = tid & 63;
  const int wid  = tid >> 6;
  const int wr   = wid >> 2;       // 0..1
  const int wc   = wid & 3;        // 0..3
  const int lc   = lane & 15;
  const int qq   = lane >> 4;      // 0..3

  f32x4 acc[4][2][3];
  #pragma unroll
  for (int a = 0; a < 4; ++a)
    #pragma unroll
    for (int b = 0; b < 2; ++b)
      #pragma unroll
      for (int g = 0; g < 3; ++g)
        acc[a][b][g] = (f32x4){0.f, 0.f, 0.f, 0.f};

  // per-wave global source base for staged weights
  const char* gB = wsB + (size_t)n0 * 128 + wid * 1024 + lane * 16;
  char* lB = lds + wid * 1024;   // per-wave LDS staging base

  auto aPtr = [&](int s) -> const float* {
    if (s < 8) return inputs + (size_t)(b0 + rowA) * 256 + s * 32 + ca * 8;
    const int ss = s - 8;
    const int kc = ss >> 3;
    const int m0 = (ss & 7) * 32;
    return children + ((size_t)kc * NB + (size_t)(b0 + rowA)) * 512 + m0 + ca * 8;
  };

  auto writeA = [&](int aoff, const f32x4& x, const f32x4& y) {
    Frag8 hi, lo;
    #pragma unroll
    for (int j = 0; j < 4; ++j) {
      __bf16 h0 = (__bf16)x[j];
      hi.v[j] = h0; lo.v[j] = (__bf16)(x[j] - (float)h0);
      __bf16 h1 = (__bf16)y[j];
      hi.v[4 + j] = h1; lo.v[4 + j] = (__bf16)(y[j] - (float)h1);
    }
    char* base = lds + aoff + rowA * 128;
    const int sw = rowA & 7;
    *(u32x4*)(base + ((ca ^ sw) << 4))       = hi.q;
    *(u32x4*)(base + (((ca | 4) ^ sw) << 4)) = lo.q;
  };

  // stage one gate's 16KB slice of B(s) into bufoff: 2 glds per wave
  auto stageGate = [&](int s, int bufoff, int gate) {
    const char* gs = gB + (size_t)s * 98304 + gate * 32768;
    char* ld = lB + bufoff + gate * 16384;
    glds16(gs,        ld);
    glds16(gs + 8192, ld + 8192);
  };

  auto readA = [&](int aoff, Frag8 (&ah)[4], Frag8 (&al)[4]) {
    #pragma unroll
    for (int rf = 0; rf < 4; ++rf) {
      const int row = wr * 64 + rf * 16 + lc;
      const char* p = lds + aoff + row * 128;
      const int sw = row & 7;
      ah[rf].q = *(const u32x4*)(p + ((qq ^ sw) << 4));
      al[rf].q = *(const u32x4*)(p + (((qq | 4) ^ sw) << 4));
    }
  };

  f32x4 rx, ry;   // A(s+1) registers

  auto doStep = [&](int s, int acur, int anxt, int bcur, int bnxt) {
    Frag8 ah[4], al[4];
    Frag8 bh[2], bl[2];
    const bool more = (s + 1 < NSTEPS);
    // ---- phi0: A-frags + gate0 B-frags ; stage gate0 of B(s+1) ----
    readA(acur, ah, al);
    read_pair<0>(lds, bcur, wc, lc, qq, bh, bl);
    if (more) stageGate(s + 1, bnxt, 0);
    PHASE_SYNC();
    __builtin_amdgcn_s_setprio(1);
    mfma_pair<0>(acc, ah, al, bh, bl);
    __builtin_amdgcn_s_setprio(0);
    // ---- phi1: gate1 B-frags ; stage gate1 ; write A(s+1) into anxt ----
    read_pair<1>(lds, bcur, wc, lc, qq, bh, bl);
    if (more) { stageGate(s + 1, bnxt, 1); writeA(anxt, rx, ry); }
    PHASE_SYNC();
    __builtin_amdgcn_s_setprio(1);
    mfma_pair<1>(acc, ah, al, bh, bl);
    __builtin_amdgcn_s_setprio(0);
    // ---- phi2: gate2 B-frags ; stage gate2 ; load A(s+2) regs ----
    read_pair<2>(lds, bcur, wc, lc, qq, bh, bl);
    if (more) stageGate(s + 1, bnxt, 2);
    { const int sl = (s + 2 < NSTEPS) ? s + 2 : NSTEPS - 1;   // clamp: keeps vmcnt count fixed
      const float* p = aPtr(sl);
      rx = *(const f32x4*)p; ry = *(const f32x4*)(p + 4); }
    PHASE_SYNC();
    __builtin_amdgcn_s_setprio(1);
    mfma_pair<2>(acc, ah, al, bh, bl);
    __builtin_amdgcn_s_setprio(0);
    // ---- step end: B(s+1) glds done (leave 2 A-loads in flight), swap-safe ----
    if (s < NSTEPS - 1) {
      asm volatile("s_waitcnt vmcnt(2)" ::: "memory");
      asm volatile("s_barrier" ::: "memory");
    }
  };

  // ---- prologue: A(0)->regs->LDS_A0, B(0)->LDS_B0, A(1)->regs ----
  { const float* p = aPtr(0); rx = *(const f32x4*)p; ry = *(const f32x4*)(p + 4); }
  stageGate(0, LDS_B0, 0);
  stageGate(0, LDS_B0, 1);
  stageGate(0, LDS_B0, 2);
  writeA(LDS_A0, rx, ry);
  { const float* p = aPtr(1); rx = *(const f32x4*)p; ry = *(const f32x4*)(p + 4); }
  asm volatile("s_waitcnt vmcnt(2) lgkmcnt(0)" ::: "memory");   // B(0) landed, A(0) written; A(1) in flight
  asm volatile("s_barrier" ::: "memory");

  #pragma unroll 1
  for (int t = 0; t < 20; ++t) {
    doStep(2 * t,     LDS_A0, LDS_A1, LDS_B0, LDS_B1);
    doStep(2 * t + 1, LDS_A1, LDS_A0, LDS_B1, LDS_B0);
  }

  // ---- epilogue ----
  #pragma unroll
  for (int cf = 0; cf < 2; ++cf) {
    const int n = n0 + wc * 32 + cf * 16 + lc;
    const float bin = bi[n], bon = bo[n], bun = bu[n];
    #pragma unroll
    for (int rf = 0; rf < 4; ++rf) {
      const int brow = b0 + wr * 64 + rf * 16 + qq * 4;
      #pragma unroll
      for (int r = 0; r < 4; ++r) {
        const float iv = acc[rf][cf][0][r] + bin;
        const float ov = acc[rf][cf][1][r] + bon;
        const float uv = acc[rf][cf][2][r] + bun;
        const float tu = 1.f - 2.f / (1.f + __expf(2.f * uv));
        const float si = 1.f / (1.f + __expf(-iv));
        const float cv = si * tu;
        const float so = 1.f / (1.f + __expf(-ov));
        const float tc = 1.f - 2.f / (1.f + __expf(2.f * cv));
        const float hv = so * tc;
        const size_t base = (size_t)(brow + r) * 512 + (size_t)n;
        out[base]       = hv;
        out[base + 256] = cv;
      }
    }
  }
}

// ================= v1 fallback (ws too small): R1 kernel =================
#define A_HI 0
#define A_LO 8192
#define B_HI 16384
#define B_LO 40960

__global__ __launch_bounds__(512, 2)
void treelstm_fused_v1(const float* __restrict__ inputs,
                       const float* __restrict__ children,
                       const float* __restrict__ Wi, const float* __restrict__ bi,
                       const float* __restrict__ Wo, const float* __restrict__ bo,
                       const float* __restrict__ Wu, const float* __restrict__ bu,
                       const float* __restrict__ Ui, const float* __restrict__ Uo,
                       const float* __restrict__ Uu,
                       float* __restrict__ out)
{
  __shared__ u32x4 lds_u4[4096];
  char* lds = (char*)lds_u4;
  const int tid = threadIdx.x;
  const int bid = blockIdx.x;
  const int wg     = (bid & 7) * 128 + (bid >> 3);
  const int strip  = wg >> 9;
  const int rowblk = wg & 511;
  const int b0 = rowblk * BM;
  const int n0 = strip * 128;
  const int rowA = tid >> 2;
  const int koff = (tid & 3) * 8;
  const float* Wg[3] = {Wi, Wo, Wu};
  const float* Ug[3] = {Ui, Uo, Uu};
  const int lane = tid & 63;
  const int wid  = tid >> 6;
  const int wr   = wid >> 2;
  const int wc   = wid & 3;
  const int lc   = lane & 15;
  const int qq   = lane >> 4;

  f32x4 acc[4][2][3];
  #pragma unroll
  for (int a = 0; a < 4; ++a)
    #pragma unroll
    for (int b = 0; b < 2; ++b)
      #pragma unroll
      for (int g = 0; g < 3; ++g)
        acc[a][b][g] = (f32x4){0.f, 0.f, 0.f, 0.f};

  float va[8];
  float vb[3][8];

  auto loadStep = [&](int s) {
    const int k0 = s * BK;
    const float* pa;
    if (s < 8) pa = inputs + (size_t)(b0 + rowA) * 256 + (k0 + koff);
    else {
      const int kc = (s - 8) >> 3;
      const int m0 = ((s - 8) & 7) * BK;
      pa = children + ((size_t)kc * NB + (size_t)(b0 + rowA)) * 512 + (m0 + koff);
    }
    f32x4 t0 = *(const f32x4*)pa;
    f32x4 t1 = *(const f32x4*)(pa + 4);
    #pragma unroll
    for (int j = 0; j < 4; ++j) { va[j] = t0[j]; va[4 + j] = t1[j]; }
    #pragma unroll
    for (int g = 0; g < 3; ++g) {
      const float* pb;
      if (s < 8) pb = Wg[g] + (size_t)(n0 + rowA) * 256 + (k0 + koff);
      else {
        const int kc = (s - 8) >> 3;
        const int m0 = ((s - 8) & 7) * BK;
        pb = Ug[g] + (size_t)kc * 65536 + (size_t)(n0 + rowA) * 256 + (m0 + koff);
      }
      f32x4 u0 = *(const f32x4*)pb;
      f32x4 u1 = *(const f32x4*)(pb + 4);
      #pragma unroll
      for (int j = 0; j < 4; ++j) { vb[g][j] = u0[j]; vb[g][4 + j] = u1[j]; }
    }
  };

  auto storeStep = [&]() {
    Frag8 h, l;
    #pragma unroll
    for (int j = 0; j < 8; ++j) {
      ushort_t hb = bf16_rne(va[j]);
      h.u[j] = hb;
      l.u[j] = bf16_rne(va[j] - bf16_f(hb));
    }
    *(u32x4*)(lds + A_HI + rowA * 64 + koff * 2) = h.q;
    *(u32x4*)(lds + A_LO + rowA * 64 + koff * 2) = l.q;
    #pragma unroll
    for (int g = 0; g < 3; ++g) {
      Frag8 hg, lg;
      #pragma unroll
      for (int j = 0; j < 8; ++j) {
        ushort_t hb = bf16_rne(vb[g][j]);
        hg.u[j] = hb;
        lg.u[j] = bf16_rne(vb[g][j] - bf16_f(hb));
      }
      *(u32x4*)(lds + B_HI + (g * 128 + rowA) * 64 + koff * 2) = hg.q;
      *(u32x4*)(lds + B_LO + (g * 128 + rowA) * 64 + koff * 2) = lg.q;
    }
  };

  auto computeStep = [&]() {
    Frag8 ah[4], al[4];
    #pragma unroll
    for (int rf = 0; rf < 4; ++rf) {
      const int row = wr * 64 + rf * 16 + lc;
      ah[rf].q = *(const u32x4*)(lds + A_HI + row * 64 + qq * 16);
      al[rf].q = *(const u32x4*)(lds + A_LO + row * 64 + qq * 16);
    }
    #pragma unroll
    for (int g = 0; g < 3; ++g) {
      #pragma unroll
      for (int cf = 0; cf < 2; ++cf) {
        const int col = wc * 32 + cf * 16 + lc;
        Frag8 bh, bl;
        bh.q = *(const u32x4*)(lds + B_HI + (g * 128 + col) * 64 + qq * 16);
        bl.q = *(const u32x4*)(lds + B_LO + (g * 128 + col) * 64 + qq * 16);
        #pragma unroll
        for (int rf = 0; rf < 4; ++rf) {
          acc[rf][cf][g] = __builtin_amdgcn_mfma_f32_16x16x32_bf16(ah[rf].v, bh.v, acc[rf][cf][g], 0, 0, 0);
          acc[rf][cf][g] = __builtin_amdgcn_mfma_f32_16x16x32_bf16(al[rf].v, bh.v, acc[rf][cf][g], 0, 0, 0);
          acc[rf][cf][g] = __builtin_amdgcn_mfma_f32_16x16x32_bf16(ah[rf].v, bl.v, acc[rf][cf][g], 0, 0, 0);
        }
      }
    }
  };

  loadStep(0);
  #pragma unroll 1
  for (int s = 0; s < NSTEPS; ++s) {
    if (s) __syncthreads();
    storeStep();
    __syncthreads();
    if (s + 1 < NSTEPS) loadStep(s + 1);
    computeStep();
  }

  #pragma unroll
  for (int cf = 0; cf < 2; ++cf) {
    const int n = n0 + wc * 32 + cf * 16 + lc;
    const float bin = bi[n], bon = bo[n], bun = bu[n];
    #pragma unroll
    for (int rf = 0; rf < 4; ++rf) {
      const int brow = b0 + wr * 64 + rf * 16 + qq * 4;
      #pragma unroll
      for (int r = 0; r < 4; ++r) {
        const float iv = acc[rf][cf][0][r] + bin;
        const float ov = acc[rf][cf][1][r] + bon;
        const float uv = acc[rf][cf][2][r] + bun;
        const float tu = 1.f - 2.f / (1.f + __expf(2.f * uv));
        const float si = 1.f / (1.f + __expf(-iv));
        const float cv = si * tu;
        const float so = 1.f / (1.f + __expf(-ov));
        const float tc = 1.f - 2.f / (1.f + __expf(2.f * cv));
        const float hv = so * tc;
        const size_t base = (size_t)(brow + r) * 512 + (size_t)n;
        out[base]       = hv;
        out[base + 256] = cv;
      }
    }
  }
}

extern "C" void kernel_launch(void* const* d_in, const int* in_sizes, int n_in,
                              void* d_out, int out_size, void* d_ws, size_t ws_size,
                              hipStream_t stream) {
  const float* inputs   = (const float*)d_in[0];
  const float* children = (const float*)d_in[1];
  const float* Wi = (const float*)d_in[3];
  const float* bi = (const float*)d_in[4];
  const float* Wo = (const float*)d_in[5];
  const float* bo = (const float*)d_in[6];
  const float* Wu = (const float*)d_in[7];
  const float* bu = (const float*)d_in[8];
  const float* Ui = (const float*)d_in[11];
  const float* Uo = (const float*)d_in[12];
  const float* Uu = (const float*)d_in[13];
  float* out = (float*)d_out;

  if (ws_size >= WS_B_BYTES) {
    char* wsB = (char*)d_ws;
    (void)hipFuncSetAttribute((const void*)treelstm_fused_v4,
                              hipFuncAttributeMaxDynamicSharedMemorySize, LDS_TOTAL);
    hipLaunchKernelGGL(prep_weights, dim3(480), dim3(256), 0, stream,
                       Wi, Wo, Wu, Ui, Uo, Uu, wsB);
    hipLaunchKernelGGL(treelstm_fused_v4, dim3(1024), dim3(512), LDS_TOTAL, stream,
                       inputs, children, wsB, bi, bo, bu, out);
  } else {
    hipLaunchKernelGGL(treelstm_fused_v1, dim3(1024), dim3(512), 0, stream,
                       inputs, children, Wi, bi, Wo, bo, Wu, bu, Ui, Uo, Uu, out);
  }
}